// Round 1
// 1631.378 us; speedup vs baseline: 1.0032x; 1.0032x over previous
//
#include <hip/hip_runtime.h>

#define BB 128
#define TT 2048
#define DD 64
#define HH 128
#define OO 32
#define NB 16
#define SCALE 2.885390081777927f   // 2/ln2 folded into weights: tanh = 1-2*rcp(1+exp2(z))

typedef _Float16 f16x8 __attribute__((ext_vector_type(8)));
typedef __fp16   pk16x2 __attribute__((ext_vector_type(2)));
typedef float    f32x4 __attribute__((ext_vector_type(4)));

#define MFMA16(a,b,c) __builtin_amdgcn_mfma_f32_16x16x32_f16((a),(b),(c),0,0,0)

__device__ __forceinline__ f32x4 load4(const float* p){ return *(const f32x4*)p; }

union U8 { uint2 u[2]; f16x8 v; };

// A-fragment for 16x16x32 (A[m=lane&15][k=(lane>>4)*8+j]), scaled on load.
__device__ __forceinline__ f16x8 afrag_s(const float* p, float s){
    float4 a = *(const float4*)p, b = *(const float4*)(p+4);
    f16x8 r;
    r[0]=(_Float16)(a.x*s); r[1]=(_Float16)(a.y*s); r[2]=(_Float16)(a.z*s); r[3]=(_Float16)(a.w*s);
    r[4]=(_Float16)(b.x*s); r[5]=(_Float16)(b.y*s); r[6]=(_Float16)(b.z*s); r[7]=(_Float16)(b.w*s);
    return r;
}

// tanh with z = SCALE*u pre-folded: e = 2^z = e^{2u}; tanh = 1 - 2/(1+e).
__device__ __forceinline__ float tanh_pre(float z){
#if __has_builtin(__builtin_amdgcn_exp2f)
    float e = __builtin_amdgcn_exp2f(z);
#else
    float e = exp2f(z);
#endif
    return __builtin_fmaf(-2.f, __builtin_amdgcn_rcpf(1.f + e), 1.f);
}

__device__ __forceinline__ unsigned pk2(float a, float b){
    union { pk16x2 h; unsigned u; } c;
    c.h = __builtin_amdgcn_cvt_pkrtz(a, b);
    return c.u;
}

// ---------------------------------------------------------------------------
// proj: xp0[bt][i] = SCALE * (W_ih0[i,:].x[bt,:] + b_ih0[i] + b_hh0[i]), fp16.
// ---------------------------------------------------------------------------
#define XSTR 72
extern "C" __global__ void __launch_bounds__(256)
proj_kernel(const float* __restrict__ x, const float* __restrict__ W_ih0,
            const float* __restrict__ b_ih0, const float* __restrict__ b_hh0,
            _Float16* __restrict__ xp0)
{
    const int tid = threadIdx.x;
    const int w = tid >> 6, lane = tid & 63;
    const int n = lane & 15, q = lane >> 4;
    const size_t row0 = (size_t)blockIdx.x * 64;

    __shared__ __align__(16) _Float16 XT[64][XSTR];

    #pragma unroll
    for (int it = 0; it < 4; ++it){
        float4 v = *(const float4*)(x + row0*DD + it*1024 + tid*4);
        int rr = it*16 + (tid >> 4), d0 = (tid & 15)*4;
        union { uint2 u; _Float16 h[4]; } c;
        c.h[0]=(_Float16)v.x; c.h[1]=(_Float16)v.y; c.h[2]=(_Float16)v.z; c.h[3]=(_Float16)v.w;
        *(uint2*)&XT[rr][d0] = c.u;
    }

    f16x8 A[8][2]; f32x4 bv[8];
    #pragma unroll
    for (int mt = 0; mt < 8; ++mt){
        #pragma unroll
        for (int kt = 0; kt < 2; ++kt)
            A[mt][kt] = afrag_s(W_ih0 + (mt*16 + n)*DD + kt*32 + q*8, SCALE);
        bv[mt] = (load4(b_ih0 + mt*16 + q*4) + load4(b_hh0 + mt*16 + q*4)) * SCALE;
    }
    __syncthreads();

    const _Float16* xr = &XT[w*16 + n][0];
    f16x8 B0 = *(const f16x8*)(xr + q*8);
    f16x8 B1 = *(const f16x8*)(xr + 32 + q*8);

    _Float16* orow = xp0 + (row0 + w*16 + n)*HH + q*4;
    #pragma unroll
    for (int mt = 0; mt < 8; ++mt){
        f32x4 acc = bv[mt];
        acc = MFMA16(A[mt][0], B0, acc);
        acc = MFMA16(A[mt][1], B1, acc);
        union { uint2 u; _Float16 h[4]; } s;
        #pragma unroll
        for (int r = 0; r < 4; ++r) s.h[r] = (_Float16)acc[r];
        *(uint2*)(orow + mt*16) = s.u;
    }
}

// ---------------------------------------------------------------------------
// fill: out[b][t][:] = b_fc for t >= lengths[b].
// ---------------------------------------------------------------------------
extern "C" __global__ void __launch_bounds__(256)
fill_kernel(const int* __restrict__ lengths, const float* __restrict__ b_fc,
            float* __restrict__ out)
{
    size_t idx = (size_t)blockIdx.x*256 + threadIdx.x;
    #pragma unroll
    for (int k = 0; k < 4; ++k, idx += (size_t)2048*256){
        int o4 = (int)(idx & 7);
        int t  = (int)((idx >> 3) & 2047);
        int b  = (int)(idx >> 14);
        if (t >= lengths[b])
            ((float4*)out)[idx] = *(const float4*)(b_fc + o4*4);
    }
}

// ---------------------------------------------------------------------------
// scan v2: wave specialization.
//   waves 0-1: layer-1 recurrence only (read H1T, write H1T)   — 16 MFMA/step
//   waves 2-3: layer-2 + FC (read H1T+H2T, write H2T, store out) — 36 MFMA/step
// State in LDS with 264B row stride (== 2 dwords mod 32 -> 16 rows hit 16
// distinct bank-pairs) read as uint2 pairs (ds_read2_b64) -> near-zero
// bank conflicts, 25% fewer state reads per step.
// ---------------------------------------------------------------------------
#define LSTR2 132               // halves per row; 264 B row stride
#define PHB   (NB*LSTR2*2)      // bytes per phase = 4224

#define STEP_L1(T_, P_, XS_) do {                                             \
    const int t_ = (T_);                                                      \
    U8 bh1[4];                                                                \
    _Pragma("unroll")                                                         \
    for (int kt = 0; kt < 4; ++kt){                                           \
        bh1[kt].u[0] = *(const uint2*)(h1b + (P_)*PHB + kt*64);               \
        bh1[kt].u[1] = *(const uint2*)(h1b + (P_)*PHB + kt*64 + 8);           \
    }                                                                         \
    f32x4 z[4];                                                               \
    const bool doZ0 = (t_ < maxlen);                                          \
    if (doZ0){                                                                \
        _Pragma("unroll")                                                     \
        for (int m = 0; m < 4; ++m){                                          \
            union { uint2 u; _Float16 h[4]; } c; c.u = XS_[m];                \
            _Pragma("unroll")                                                 \
            for (int r = 0; r < 4; ++r) z[m][r] = (float)c.h[r];              \
        }                                                                     \
        _Pragma("unroll")                                                     \
        for (int kt = 0; kt < 4; ++kt)                                        \
            _Pragma("unroll")                                                 \
            for (int m = 0; m < 4; ++m)                                       \
                z[m] = MFMA16(A0[m][kt], bh1[kt].v, z[m]);                    \
    }                                                                         \
    {   /* unconditional clamped reload into the SAME named slots */          \
        const int tl = (t_ + 2 < TT) ? (t_ + 2) : (TT - 1);                   \
        _Pragma("unroll")                                                     \
        for (int m = 0; m < 4; ++m)                                           \
            XS_[m] = *(const uint2*)(xpb + (size_t)tl*256 + m*32);            \
    }                                                                         \
    if (doZ0){                                                                \
        _Pragma("unroll")                                                     \
        for (int m = 0; m < 4; ++m){                                          \
            uint2 v;                                                          \
            v.x = pk2(tanh_pre(z[m][0]), tanh_pre(z[m][1]));                  \
            v.y = pk2(tanh_pre(z[m][2]), tanh_pre(z[m][3]));                  \
            *(uint2*)((char*)H1T + ((P_)^1)*PHB + n*264 + (w*4+m)*32 + q*8) = v; \
        }                                                                     \
    }                                                                         \
    asm volatile("s_waitcnt lgkmcnt(0)\n\ts_barrier" ::: "memory");           \
} while (0)

#define STEP_L2(T_, P_) do {                                                  \
    const int t_ = (T_);                                                      \
    U8 bh1[4], bh2[4];                                                        \
    _Pragma("unroll")                                                         \
    for (int kt = 0; kt < 4; ++kt){                                           \
        bh1[kt].u[0] = *(const uint2*)(h1b + (P_)*PHB + kt*64);               \
        bh1[kt].u[1] = *(const uint2*)(h1b + (P_)*PHB + kt*64 + 8);           \
        bh2[kt].u[0] = *(const uint2*)(h2b + (P_)*PHB + kt*64);               \
        bh2[kt].u[1] = *(const uint2*)(h2b + (P_)*PHB + kt*64 + 8);           \
    }                                                                         \
    const bool doZ1 = (t_ >= 1) && (t_ <= maxlen);                            \
    f32x4 z[4];                                                               \
    if (doZ1){                                                                \
        f32x4 y[4];                                                           \
        _Pragma("unroll")                                                     \
        for (int m = 0; m < 4; ++m){                                          \
            z[m] = b1v[m];                                                    \
            y[m][0]=0.f; y[m][1]=0.f; y[m][2]=0.f; y[m][3]=0.f;               \
        }                                                                     \
        _Pragma("unroll")                                                     \
        for (int kt = 0; kt < 4; ++kt)                                        \
            _Pragma("unroll")                                                 \
            for (int m = 0; m < 4; ++m){                                      \
                z[m] = MFMA16(Ai[m][kt], bh1[kt].v, z[m]);                    \
                y[m] = MFMA16(Ah[m][kt], bh2[kt].v, y[m]);                    \
            }                                                                 \
        _Pragma("unroll")                                                     \
        for (int m = 0; m < 4; ++m) z[m] += y[m];                             \
    }                                                                         \
    if (t_ >= 2){                                                             \
        f32x4 zf = bfv;                                                       \
        _Pragma("unroll")                                                     \
        for (int kt = 0; kt < 4; ++kt) zf = MFMA16(Af[kt], bh2[kt].v, zf);    \
        if (t_ - 2 < lenn){                                                   \
            float4 sv; sv.x=zf[0]; sv.y=zf[1]; sv.z=zf[2]; sv.w=zf[3];        \
            *(float4*)(obase + (size_t)(t_-2)*OO) = sv;                       \
        }                                                                     \
    }                                                                         \
    if (doZ1){                                                                \
        _Pragma("unroll")                                                     \
        for (int m = 0; m < 4; ++m){                                          \
            uint2 v;                                                          \
            v.x = pk2(tanh_pre(z[m][0]), tanh_pre(z[m][1]));                  \
            v.y = pk2(tanh_pre(z[m][2]), tanh_pre(z[m][3]));                  \
            *(uint2*)((char*)H2T + ((P_)^1)*PHB + n*264 + (wl*4+m)*32 + q*8) = v; \
        }                                                                     \
    }                                                                         \
    asm volatile("s_waitcnt lgkmcnt(0)\n\ts_barrier" ::: "memory");           \
} while (0)

extern "C" __global__ void __launch_bounds__(256, 1)
scan_kernel(const _Float16* __restrict__ xp0, const int* __restrict__ lengths,
            const float* __restrict__ W_hh0,
            const float* __restrict__ W_ih1, const float* __restrict__ W_hh1,
            const float* __restrict__ b_ih1, const float* __restrict__ b_hh1,
            const float* __restrict__ W_fc,  const float* __restrict__ b_fc,
            float* __restrict__ out)
{
    const int tid  = threadIdx.x;
    const int w    = tid >> 6, lane = tid & 63;
    const int n    = lane & 15, q = lane >> 4;
    const int rbase= blockIdx.x * NB;

    __shared__ __align__(16) _Float16 H1T[2][NB][LSTR2];
    __shared__ __align__(16) _Float16 H2T[2][NB][LSTR2];

    for (int idx = tid; idx < (2*NB*LSTR2)/2; idx += 256){
        ((unsigned*)H1T)[idx] = 0u;
        ((unsigned*)H2T)[idx] = 0u;
    }

    const int lenn = lengths[rbase + n];
    int mx = lenn;
    #pragma unroll
    for (int s = 1; s < 16; s <<= 1){ int o = __shfl_xor(mx, s, 64); mx = max(mx, o); }
    const int maxlen = __builtin_amdgcn_readfirstlane(mx);

    const char* h1b = (const char*)H1T + n*264 + q*16;
    const char* h2b = (const char*)H2T + n*264 + q*16;

    __syncthreads();

    if (w < 2){
        // ---- layer-1 waves: 4 m-tiles each (hidden w*64 .. w*64+63) ----
        f16x8 A0[4][4];
        #pragma unroll
        for (int m = 0; m < 4; ++m){
            const int row = (w*4 + m)*16 + n;
            #pragma unroll
            for (int kt = 0; kt < 4; ++kt)
                A0[m][kt] = afrag_s(W_hh0 + row*HH + kt*32 + q*8, SCALE);
        }
        const char* xpb = (const char*)(xp0 + ((size_t)(rbase+n)*TT)*HH)
                          + (w*4)*32 + q*8;

        uint2 xe[4], xo[4];
        #pragma unroll
        for (int m = 0; m < 4; ++m){
            xe[m] = *(const uint2*)(xpb + m*32);
            xo[m] = *(const uint2*)(xpb + 256 + m*32);
        }

        for (int t0 = 0; t0 <= maxlen + 1; t0 += 2){
            STEP_L1(t0,     0, xe);
            STEP_L1(t0 + 1, 1, xo);
        }
    } else {
        // ---- layer-2 + FC waves ----
        const int wl = w - 2, f = w & 1;
        f16x8 Ai[4][4], Ah[4][4];
        f32x4 b1v[4];
        #pragma unroll
        for (int m = 0; m < 4; ++m){
            const int row = (wl*4 + m)*16 + n;
            #pragma unroll
            for (int kt = 0; kt < 4; ++kt){
                Ai[m][kt] = afrag_s(W_ih1 + row*HH + kt*32 + q*8, SCALE);
                Ah[m][kt] = afrag_s(W_hh1 + row*HH + kt*32 + q*8, SCALE);
            }
            b1v[m] = (load4(b_ih1 + (wl*4+m)*16 + q*4)
                    + load4(b_hh1 + (wl*4+m)*16 + q*4)) * SCALE;
        }
        f16x8 Af[4];
        #pragma unroll
        for (int kt = 0; kt < 4; ++kt)
            Af[kt] = afrag_s(W_fc + (f*16 + n)*HH + kt*32 + q*8, 1.0f);
        const f32x4 bfv = load4(b_fc + f*16 + q*4);

        float* obase = out + ((size_t)(rbase+n)*TT)*OO + f*16 + q*4;

        for (int t0 = 0; t0 <= maxlen + 1; t0 += 2){
            STEP_L2(t0,     0);
            STEP_L2(t0 + 1, 1);
        }
    }
}

// ---------------------------------------------------------------------------
extern "C" void kernel_launch(void* const* d_in, const int* in_sizes, int n_in,
                              void* d_out, int out_size, void* d_ws, size_t ws_size,
                              hipStream_t stream)
{
    const float* x       = (const float*)d_in[0];
    const int*   lengths = (const int*)  d_in[1];
    const float* W_ih0   = (const float*)d_in[2];
    const float* W_hh0   = (const float*)d_in[3];
    const float* b_ih0   = (const float*)d_in[4];
    const float* b_hh0   = (const float*)d_in[5];
    const float* W_ih1   = (const float*)d_in[6];
    const float* W_hh1   = (const float*)d_in[7];
    const float* b_ih1   = (const float*)d_in[8];
    const float* b_hh1   = (const float*)d_in[9];
    const float* W_fc    = (const float*)d_in[10];
    const float* b_fc    = (const float*)d_in[11];

    _Float16* xp = (_Float16*)d_ws;   // [B*T][128] fp16 = 64 MiB (pre-scaled)

    proj_kernel<<<BB*TT/64, 256, 0, stream>>>(x, W_ih0, b_ih0, b_hh0, xp);
    fill_kernel<<<2048, 256, 0, stream>>>(lengths, b_fc, (float*)d_out);
    scan_kernel<<<BB/NB, 256, 0, stream>>>(xp, lengths, W_hh0,
                                           W_ih1, W_hh1, b_ih1, b_hh1,
                                           W_fc, b_fc, (float*)d_out);
}